// Round 13
// baseline (2098.267 us; speedup 1.0000x reference)
//
#include <hip/hip_runtime.h>
#include <math.h>

#define NEGV -1000000000.0f

typedef short short8 __attribute__((ext_vector_type(8)));
typedef float floatx4 __attribute__((ext_vector_type(4)));

__device__ __forceinline__ float sigm(float x){ return 1.0f/(1.0f+expf(-x)); }
__device__ __forceinline__ void edge_sd(int e,const int* src,const int* dst,int E,int& s,int& d){
  if(e<E){ s=src[e]; d=dst[e]; } else { s=e-E; d=s; }
}
__device__ __forceinline__ ushort bf16rn(float x){
  unsigned u = __float_as_uint(x);
  unsigned r = (u + 0x7fffu + ((u>>16)&1u)) >> 16;
  return (ushort)r;
}
__device__ __forceinline__ float bf16f(ushort h){ return __uint_as_float(((unsigned)h)<<16); }

__global__ void k_zero(float* __restrict__ p, size_t n){
  size_t i = (size_t)blockIdx.x*256 + threadIdx.x;
  if (i < n) p[i] = 0.0f;
}

// ---------------- bf16x3 conversions ----------------
__global__ void k_split3(const float* __restrict__ src,int R,int Cs,int ld,
                         ushort* __restrict__ dst,int Cp,int bmode){
  int idx = blockIdx.x*256+threadIdx.x;
  if (idx >= R*Cp) return;
  int r = idx / Cp, c = idx - r*Cp;
  float x = (c < Cs) ? src[(size_t)r*ld + c] : 0.0f;
  ushort h = bf16rn(x);
  ushort l = bf16rn(x - bf16f(h));
  size_t base = (size_t)r*(3*Cp) + c;
  dst[base]        = h;
  dst[base + Cp]   = bmode ? l : h;
  dst[base + 2*Cp] = bmode ? h : l;
}
// Sp = exp(src[:,perm]-mcol[perm])*invd[perm], transposed to K-innermost; writes BOTH
// A-role (dstA) and B-role (dstB); zero-pads k>=Rs rows in dstA/dstB AND dstCpad.
__global__ void k_split3_Tdual(const float* __restrict__ src,int Rs,int Cs,int ld,
                               const int* __restrict__ gperm,const float* __restrict__ cscale,
                               const float* __restrict__ emax,
                               ushort* __restrict__ dstA,ushort* __restrict__ dstB,
                               ushort* __restrict__ dstCpad,int Kp){
  __shared__ float t[32][33];
  int tx = threadIdx.x & 31, ty = threadIdx.x >> 5;
  int kb = blockIdx.y*32, xb = blockIdx.x*32;
  int x = xb + tx;
  int gx = (x < Cs) ? gperm[x] : 0;
#pragma unroll
  for (int i=0;i<4;i++){
    int k = kb + ty + i*8;
    t[ty+i*8][tx] = (k < Rs && x < Cs) ? src[(size_t)k*ld + gx] : 0.0f;
  }
  __syncthreads();
  const int K3 = 3*Kp;
#pragma unroll
  for (int i=0;i<4;i++){
    int xo = xb + ty + i*8, ko = kb + tx;
    if (xo < Cs){
      float v = 0.0f;
      if (ko < Rs){
        int g = gperm[xo];
        v = expf(t[tx][ty+i*8] - emax[g]) * cscale[g];
      }
      ushort h = bf16rn(v);
      ushort l = bf16rn(v - bf16f(h));
      size_t base = (size_t)xo*K3 + ko;
      dstA[base] = h; dstA[base+Kp] = h; dstA[base+2*Kp] = l;
      dstB[base] = h; dstB[base+Kp] = l; dstB[base+2*Kp] = h;
      if (ko >= Rs){ dstCpad[base]=0; dstCpad[base+Kp]=0; dstCpad[base+2*Kp]=0; }
    }
  }
}

// ---------------- MFMA bf16 GEMM (64x64 tile, K-step 64, double-buffered) ----------------
// EPI 1: mask(A+I)+leakyrelu; EPI 2: zero diag.
template<int EPI>
__global__ __launch_bounds__(256) void k_gemm_mfma(
    const ushort* __restrict__ A, const ushort* __restrict__ B,
    float* __restrict__ C, int ldc, int M, int N, int K3,
    const float* __restrict__ mask, int ldm)
{
  __shared__ ushort As[2][64][72];
  __shared__ ushort Bs[2][64][72];
  const int tid = threadIdx.x;
  const int m0 = blockIdx.y*64, n0 = blockIdx.x*64;
  const int w = tid>>6, lane = tid&63;
  const int lo4 = lane&15, quad = lane>>4;
  const int sr = tid>>2, sseg = tid&3;

  floatx4 acc[4];
#pragma unroll
  for(int c=0;c<4;c++){ acc[c][0]=0.f; acc[c][1]=0.f; acc[c][2]=0.f; acc[c][3]=0.f; }

  const size_t arow = (size_t)(m0+sr)*K3;
  const size_t brow = (size_t)(n0+sr)*K3;
  const bool aval = (m0+sr) < M;
  const bool bval = (n0+sr) < N;

  uint4 av0 = make_uint4(0,0,0,0), av1 = make_uint4(0,0,0,0);
  uint4 bv0 = make_uint4(0,0,0,0), bv1 = make_uint4(0,0,0,0);
  if (aval){ av0 = *(const uint4*)(A + arow + sseg*8);
             av1 = *(const uint4*)(A + arow + 32 + sseg*8); }
  if (bval){ bv0 = *(const uint4*)(B + brow + sseg*8);
             bv1 = *(const uint4*)(B + brow + 32 + sseg*8); }
  *(uint4*)&As[0][sr][sseg*8] = av0; *(uint4*)&As[0][sr][32+sseg*8] = av1;
  *(uint4*)&Bs[0][sr][sseg*8] = bv0; *(uint4*)&Bs[0][sr][32+sseg*8] = bv1;
  __syncthreads();

  const int T = K3 >> 6;
  for (int i=0;i<T;i++){
    const int cb = i & 1;
    if (i+1 < T){
      const int k0 = (i+1)<<6;
      av0 = make_uint4(0,0,0,0); av1 = make_uint4(0,0,0,0);
      bv0 = make_uint4(0,0,0,0); bv1 = make_uint4(0,0,0,0);
      if (aval){ av0 = *(const uint4*)(A + arow + k0 + sseg*8);
                 av1 = *(const uint4*)(A + arow + k0 + 32 + sseg*8); }
      if (bval){ bv0 = *(const uint4*)(B + brow + k0 + sseg*8);
                 bv1 = *(const uint4*)(B + brow + k0 + 32 + sseg*8); }
    }
    short8 af0 = *(const short8*)&As[cb][16*w + lo4][quad*8];
    short8 af1 = *(const short8*)&As[cb][16*w + lo4][32+quad*8];
#pragma unroll
    for (int c=0;c<4;c++){
      short8 bf0 = *(const short8*)&Bs[cb][16*c + lo4][quad*8];
      acc[c] = __builtin_amdgcn_mfma_f32_16x16x32_bf16(af0, bf0, acc[c], 0, 0, 0);
      short8 bf1 = *(const short8*)&Bs[cb][16*c + lo4][32+quad*8];
      acc[c] = __builtin_amdgcn_mfma_f32_16x16x32_bf16(af1, bf1, acc[c], 0, 0, 0);
    }
    if (i+1 < T){
      __syncthreads();
      *(uint4*)&As[1-cb][sr][sseg*8] = av0; *(uint4*)&As[1-cb][sr][32+sseg*8] = av1;
      *(uint4*)&Bs[1-cb][sr][sseg*8] = bv0; *(uint4*)&Bs[1-cb][sr][32+sseg*8] = bv1;
      __syncthreads();
    }
  }

#pragma unroll
  for (int c=0;c<4;c++){
    const int gn = n0 + 16*c + lo4;
#pragma unroll
    for (int r=0;r<4;r++){
      const int gm = m0 + 16*w + quad*4 + r;
      if (gm < M && gn < N){
        float v = acc[c][r];
        if (EPI==1) v = (mask[(size_t)gm*ldm+gn] != 0.0f || gm==gn) ? (v > 0.0f ? v : 0.2f*v) : NEGV;
        if (EPI==2 && gm==gn) v = 0.0f;
        C[(size_t)gm*ldc+gn] = v;
      }
    }
  }
}

// TB = A@Sp + Sp (fp32 acc), double-buffered; output written directly as bf16x3
// B-role TRANSPOSED. Sp re-read from its B-role bf16x3 (h+l) at the output addresses.
__global__ __launch_bounds__(256) void k_gemm_mfma_tb(
    const ushort* __restrict__ A, const ushort* __restrict__ B,
    ushort* __restrict__ Cb, int Kp, int M, int N, int K3)
{
  __shared__ ushort As[2][64][72];
  __shared__ ushort Bs[2][64][72];
  const int tid = threadIdx.x;
  const int m0 = blockIdx.y*64, n0 = blockIdx.x*64;
  const int w = tid>>6, lane = tid&63;
  const int lo4 = lane&15, quad = lane>>4;
  const int sr = tid>>2, sseg = tid&3;

  floatx4 acc[4];
#pragma unroll
  for(int c=0;c<4;c++){ acc[c][0]=0.f; acc[c][1]=0.f; acc[c][2]=0.f; acc[c][3]=0.f; }

  const size_t arow = (size_t)(m0+sr)*K3;
  const size_t brow = (size_t)(n0+sr)*K3;
  const bool aval = (m0+sr) < M;
  const bool bval = (n0+sr) < N;

  uint4 av0 = make_uint4(0,0,0,0), av1 = make_uint4(0,0,0,0);
  uint4 bv0 = make_uint4(0,0,0,0), bv1 = make_uint4(0,0,0,0);
  if (aval){ av0 = *(const uint4*)(A + arow + sseg*8);
             av1 = *(const uint4*)(A + arow + 32 + sseg*8); }
  if (bval){ bv0 = *(const uint4*)(B + brow + sseg*8);
             bv1 = *(const uint4*)(B + brow + 32 + sseg*8); }
  *(uint4*)&As[0][sr][sseg*8] = av0; *(uint4*)&As[0][sr][32+sseg*8] = av1;
  *(uint4*)&Bs[0][sr][sseg*8] = bv0; *(uint4*)&Bs[0][sr][32+sseg*8] = bv1;
  __syncthreads();

  const int T = K3 >> 6;
  for (int i=0;i<T;i++){
    const int cb = i & 1;
    if (i+1 < T){
      const int k0 = (i+1)<<6;
      av0 = make_uint4(0,0,0,0); av1 = make_uint4(0,0,0,0);
      bv0 = make_uint4(0,0,0,0); bv1 = make_uint4(0,0,0,0);
      if (aval){ av0 = *(const uint4*)(A + arow + k0 + sseg*8);
                 av1 = *(const uint4*)(A + arow + k0 + 32 + sseg*8); }
      if (bval){ bv0 = *(const uint4*)(B + brow + k0 + sseg*8);
                 bv1 = *(const uint4*)(B + brow + k0 + 32 + sseg*8); }
    }
    short8 af0 = *(const short8*)&As[cb][16*w + lo4][quad*8];
    short8 af1 = *(const short8*)&As[cb][16*w + lo4][32+quad*8];
#pragma unroll
    for (int c=0;c<4;c++){
      short8 bf0 = *(const short8*)&Bs[cb][16*c + lo4][quad*8];
      acc[c] = __builtin_amdgcn_mfma_f32_16x16x32_bf16(af0, bf0, acc[c], 0, 0, 0);
      short8 bf1 = *(const short8*)&Bs[cb][16*c + lo4][32+quad*8];
      acc[c] = __builtin_amdgcn_mfma_f32_16x16x32_bf16(af1, bf1, acc[c], 0, 0, 0);
    }
    if (i+1 < T){
      __syncthreads();
      *(uint4*)&As[1-cb][sr][sseg*8] = av0; *(uint4*)&As[1-cb][sr][32+sseg*8] = av1;
      *(uint4*)&Bs[1-cb][sr][sseg*8] = bv0; *(uint4*)&Bs[1-cb][sr][32+sseg*8] = bv1;
      __syncthreads();
    }
  }

  const int K3o = 3*Kp;
#pragma unroll
  for (int c=0;c<4;c++){
    const int gn = n0 + 16*c + lo4;
    if (gn < N){
#pragma unroll
      for (int r=0;r<4;r++){
        const int gm = m0 + 16*w + quad*4 + r;
        if (gm < M){
          size_t base = (size_t)gn*K3o + gm;
          float sp = bf16f(B[base]) + bf16f(B[base+Kp]);   // Sp at (gm,gn)
          float v = acc[c][r] + sp;
          ushort h = bf16rn(v);
          ushort l = bf16rn(v - bf16f(h));
          Cb[base] = h; Cb[base+Kp] = l; Cb[base+2*Kp] = h;
        }
      }
    }
  }
}

// ---------------- atomic-free skinny agg GEMM (pool paths) ----------------
template<bool MAXM, bool COUNT, bool EXPM, bool SELF>
__global__ __launch_bounds__(256) void k_skinny(
    const float* __restrict__ A, int lda,
    const float* __restrict__ X,
    const float* __restrict__ mcol,
    float* __restrict__ P, int* __restrict__ cntp,
    int M, int K, int kchunk)
{
  __shared__ float As[16][68];
  __shared__ float Xs[16][68];
  const int tid = threadIdx.x;
  const int m0 = blockIdx.y * 64;
  const int tmb = (tid & 15) * 4, tnb = (tid >> 4) * 4;
  float acc[4][4];
  int cacc[4] = {0,0,0,0};
#pragma unroll
  for (int i=0;i<4;i++)
#pragma unroll
    for (int j=0;j<4;j++) acc[i][j] = MAXM ? NEGV : 0.0f;

  const int kstart = blockIdx.z * kchunk;
  int kend = kstart + kchunk; if (kend > K) kend = K;
  const int ml = tid & 63, tb = tid >> 6;
  const bool mvalid = (m0 + ml) < M;
  float mc = 0.0f;
  if (EXPM && mvalid) mc = mcol[m0 + ml];

  for (int k0 = kstart; k0 < kend; k0 += 16) {
#pragma unroll
    for (int s=0;s<4;s++) {
      const int tk = tb + s*4;
      float va = 0.0f, vx = 0.0f;
      if ((k0+tk) < K) {
        if (mvalid){
          va = A[(size_t)(k0+tk)*lda + m0 + ml];
          if (EXPM) va = expf(va - mc);
        }
        vx = X[(size_t)(k0+tk)*64 + ml];
      }
      As[tk][ml] = va;
      Xs[tk][ml] = vx;
    }
    __syncthreads();
#pragma unroll
    for (int kk=0; kk<16; kk++) {
      const float4 a4 = *(const float4*)&As[kk][tmb];
      const float4 b4 = *(const float4*)&Xs[kk][tnb];
      const float av[4] = {a4.x,a4.y,a4.z,a4.w};
      const float bv[4] = {b4.x,b4.y,b4.z,b4.w};
#pragma unroll
      for (int i=0;i<4;i++){
        if (COUNT) cacc[i] += (av[i] != 0.0f) ? 1 : 0;
#pragma unroll
        for (int j=0;j<4;j++) {
          if (MAXM) acc[i][j] = fmaxf(acc[i][j], av[i] != 0.0f ? bv[j] : NEGV);
          else      acc[i][j] = fmaf(av[i], bv[j], acc[i][j]);
        }
      }
    }
    __syncthreads();
  }

  const size_t slab = (size_t)blockIdx.z * M * 64;
#pragma unroll
  for (int i=0;i<4;i++){
    const int m = m0 + tmb + i;
    if (m < M){
#pragma unroll
      for (int j=0;j<4;j++){
        float v = acc[i][j];
        if (SELF) v = fmaxf(v, X[(size_t)m*64 + tnb + j]);
        P[slab + (size_t)m*64 + tnb + j] = v;
      }
    }
  }
  if (COUNT && tnb == 0){
#pragma unroll
    for (int i=0;i<4;i++){
      const int m = m0 + tmb + i;
      if (m < M) cntp[blockIdx.z*M + m] = cacc[i];
    }
  }
}

// ---------------- fused dense gconv: ONE kernel ----------------
// block = 4 rows x 64 cols. agg[i][j] = sum_k A[i][k] X[k][j]; cnt = #nz(A row);
// then v = relu(agg@Wrel/cnt + brel + Xrow@Wroot), mean-accumulate.
__global__ __launch_bounds__(256) void k_gconv_one(
    const float* __restrict__ A, const float* __restrict__ X,
    const float* __restrict__ Wrel, const float* __restrict__ brel,
    const float* __restrict__ Wroot,
    float* __restrict__ XN, int n, float* __restrict__ meanacc, float inv_n)
{
  __shared__ float Xs[64][65];
  __shared__ float As[4][64];
  __shared__ float aggS[4][65];
  __shared__ float xrow[4][65];
  __shared__ float cntS[4];
  const int tid = threadIdx.x;
  const int r = tid>>6, j = tid&63;
  const int i = blockIdx.x*4 + r;
  const bool iv = (i < n);
  float acc = 0.0f; int cnt = 0;

  for (int k0 = 0; k0 < n; k0 += 64){
    const int kmax = (n - k0 < 64) ? (n - k0) : 64;
#pragma unroll
    for (int s2=0;s2<16;s2++){
      const int kk = r + 4*s2;
      const int k = k0 + kk;
      Xs[kk][j] = (k < n) ? X[(size_t)k*64 + j] : 0.0f;
    }
    As[r][j] = (iv && (k0 + j) < n) ? A[(size_t)i*n + k0 + j] : 0.0f;
    __syncthreads();
    if (iv){
      for (int kk=0; kk<kmax; kk++){
        const float a = As[r][kk];
        cnt += (a != 0.0f) ? 1 : 0;
        acc = fmaf(a, Xs[kk][j], acc);
      }
    }
    __syncthreads();
  }

  aggS[r][j] = acc;
  xrow[r][j] = iv ? X[(size_t)i*64 + j] : 0.0f;
  if (j == 0) cntS[r] = (float)(cnt > 1 ? cnt : 1);
  __syncthreads();
  float v = 0.0f;
  if (iv){
    float a2 = 0.0f, rt = 0.0f;
    for(int q=0;q<64;q++){
      a2 = fmaf(aggS[r][q], Wrel[q*64+j], a2);
      rt = fmaf(xrow[r][q], Wroot[q*64+j], rt);
    }
    v = fmaxf(a2/cntS[r] + brel[j] + rt, 0.0f);
    XN[(size_t)i*64+j] = v;
  }
  __syncthreads();
  aggS[r][j] = v;
  __syncthreads();
  if (r == 0) atomicAdd(&meanacc[j], (aggS[0][j]+aggS[1][j]+aggS[2][j]+aggS[3][j])*inv_n);
}

// slab max-reduce -> xq; xq2 = xq@pW+pb; cntP = 1 + sum counts.
// Also emits bf16x3 operands: dstA (A-role from X), dstB (B-role from xq2).
__global__ __launch_bounds__(256) void k_poolq(
    const float* __restrict__ SEGP,const int* __restrict__ cntp8,int Z,
    const float* __restrict__ pWp,const float* __restrict__ pbp,
    const float* __restrict__ X,
    ushort* __restrict__ dstA,ushort* __restrict__ dstB,
    float* __restrict__ cntP,int n)
{
  __shared__ float xq[4][65];
  const int tid = threadIdx.x;
  const int r = tid>>6, j = tid&63;
  const int i = blockIdx.x*4 + r;
  float v = NEGV;
  if (i < n){
    for(int z=0;z<Z;z++) v = fmaxf(v, SEGP[(size_t)z*n*64 + (size_t)i*64 + j]);
    if (j == 0){
      int c=1; for(int z=0;z<Z;z++) c += cntp8[z*n+i];
      cntP[i] = (float)c;
    }
  }
  xq[r][j] = v;
  __syncthreads();
  if (i < n){
    float s = pbp[j];
    for(int q=0;q<64;q++) s = fmaf(xq[r][q], pWp[q*64+j], s);
    size_t base = (size_t)i*192 + j;
    ushort h = bf16rn(s), l = bf16rn(s - bf16f(h));
    dstB[base] = h; dstB[base+64] = l; dstB[base+128] = h;
    float x = X[(size_t)i*64 + j];
    h = bf16rn(x); l = bf16rn(x - bf16f(h));
    dstA[base] = h; dstA[base+64] = h; dstA[base+128] = l;
  }
}

// ---------------- fused column softmax stats (ONE kernel) ----------------
__global__ __launch_bounds__(256) void k_smax_fused(const float* __restrict__ S,int n,
                                                    float* __restrict__ mcol,float* __restrict__ invd){
  __shared__ float red[16][17];
  const int jc = threadIdx.x & 15, rg = threadIdx.x >> 4;
  const int j = blockIdx.x*16 + jc;
  float m = -3.0e38f;
  if (j < n)
    for(int i=rg;i<n;i+=16) m = fmaxf(m, S[(size_t)i*n+j]);
  red[rg][jc] = m;
  __syncthreads();
  for(int s=8;s>0;s>>=1){
    if(rg<s) red[rg][jc] = fmaxf(red[rg][jc], red[rg+s][jc]);
    __syncthreads();
  }
  const float mc = red[0][jc];
  __syncthreads();
  float sum = 0.0f;
  if (j < n)
    for(int i=rg;i<n;i+=16) sum += expf(S[(size_t)i*n+j]-mc);
  red[rg][jc] = sum;
  __syncthreads();
  for(int s=8;s>0;s>>=1){
    if(rg<s) red[rg][jc] += red[rg+s][jc];
    __syncthreads();
  }
  if(rg==0 && j<n){ mcol[j]=mc; invd[j]=1.0f/red[0][jc]; }
}

// slab sum * invd -> XC; then aN/bN/cN per row; zeroes pcnt.
__global__ __launch_bounds__(256) void k_xcabc_dense(
    const float* __restrict__ SEGP,int Z,const float* __restrict__ invd,
    float* __restrict__ XC,
    const float* __restrict__ w1,const float* bb1,const float* __restrict__ w2,
    const float* __restrict__ w3,const float* bb3,
    float* aN,float* bN,float* cN,int* pcnt,int n)
{
  __shared__ float xc[4][65];
  const int tid = threadIdx.x;
  const int r = tid>>6, j = tid&63;
  const int i = blockIdx.x*4 + r;
  if (blockIdx.x==0 && tid==0) *pcnt = 0;
  float v = 0.0f;
  if (i < n){
    for(int z=0;z<Z;z++) v += SEGP[(size_t)z*n*64 + (size_t)i*64 + j];
    v *= invd[i];
    XC[(size_t)i*64+j] = v;
  }
  xc[r][j] = v;
  __syncthreads();
  if (i < n && j < 3){
    float s = (j==0)?bb1[0]:((j==2)?bb3[0]:0.0f);
    const float* w = (j==0)?w1:((j==1)?w2:w3);
    for(int q=0;q<64;q++) s = fmaf(xc[r][q], w[q], s);
    if(j==0) aN[i]=s; else if(j==1) bN[i]=s; else cN[i]=s;
  }
}

__global__ void k_aggcol(const float* __restrict__ A,const float* __restrict__ aN,
                         float* __restrict__ aggp,int n){
  int idx = blockIdx.x*256+threadIdx.x; if(idx>=n*16) return;
  int j = idx % n, c = idx / n;
  int i0 = (int)(((long long)n*c)/16), i1 = (int)(((long long)n*(c+1))/16);
  float s = 0.0f;
  for(int i=i0;i<i1;i++) if(A[(size_t)i*n + j] != 0.0f) s += aN[i];
  aggp[c*n + j] = s;
}

// fit (MODE 1: from aggp slabs; MODE 0: given) + rank + perm slot + XN write, one kernel.
template<int MODE>
__global__ __launch_bounds__(256) void k_rank_fused(
    const float* __restrict__ fit_in,
    const float* __restrict__ aggp,const float* __restrict__ cntP,
    const float* __restrict__ aN,const float* __restrict__ bN,const float* __restrict__ cN,
    const float* __restrict__ XC,float* __restrict__ XN,
    int n,int k,int* pcnt,int* perm)
{
  __shared__ float fs[1504];
  const int tid = threadIdx.x;
  for(int u=tid; u<n; u+=256){
    float f;
    if (MODE==0) f = fit_in[u];
    else {
      float a = aN[u];
      for(int c=0;c<16;c++) a += aggp[c*n+u];
      f = sigm(a - cntP[u]*bN[u] + cN[u]);
    }
    fs[u] = f;
  }
  __syncthreads();
  const int v = blockIdx.x*256+tid; if(v>=n) return;
  const float fv = fs[v]; int r = 0;
  for(int u=0;u<n;u++){ float fu = fs[u]; r += (fu > fv || (fu == fv && u < v)) ? 1 : 0; }
  if (r < k){
    int p = atomicAdd(pcnt,1);
    perm[p] = v;
    const float* src = XC + (size_t)v*64;
    float* d = XN + (size_t)p*64;
    for(int h=0;h<64;h++) d[h] = src[h]*fv;
  }
}

// ---------------- prologue: degrees + CSR over L=E+n edges (incl self) ----------------
__global__ void k_deg(const int* __restrict__ src,const int* __restrict__ dst,int* indeg,int* outdeg,int E){
  int e = blockIdx.x*256+threadIdx.x; if(e>=E) return;
  atomicAdd(&indeg[dst[e]],1); atomicAdd(&outdeg[src[e]],1);
}
__global__ __launch_bounds__(256) void k_prefix2(const int* __restrict__ indeg,const int* __restrict__ outdeg,
                          int* offD,int* curD,int* offS,int* curS,int n){
  __shared__ int ds[1504];
  const int* dsrc = blockIdx.y ? outdeg : indeg;
  for(int u=threadIdx.x; u<n; u+=256) ds[u] = dsrc[u];
  __syncthreads();
  int t = blockIdx.x*256+threadIdx.x; if(t>n) return;
  int s = 0;
  for(int u=0;u<t;u++) s += ds[u]+1;
  if (blockIdx.y){ offS[t]=s; if(t<n) curS[t]=s; }
  else           { offD[t]=s; if(t<n) curD[t]=s; }
}
__global__ void k_csr_fill2(const int* src,const int* dst,
                            int* curS,int* colS,int* eidS,
                            int* curD,int* rowD,int* eidD,int E,int n){
  int e = blockIdx.x*256+threadIdx.x; if(e>=E+n) return;
  int s,d; edge_sd(e,src,dst,E,s,d);
  int p = atomicAdd(&curS[s],1); colS[p]=d; eidS[p]=e;
  int q = atomicAdd(&curD[d],1); rowD[q]=s; eidD[q]=e;
}

__global__ void k_mm_small(const float* __restrict__ A,const float* __restrict__ W,
                           const float* __restrict__ b,float* __restrict__ C,
                           int M,int K,int Np,int act){
  int idx = blockIdx.x*256+threadIdx.x; if(idx>=M*Np) return;
  int m = idx/Np, j = idx - m*Np;
  float s = b ? b[j] : 0.0f;
  const float* a = A + (size_t)m*K;
  for(int q=0;q<K;q++) s = fmaf(a[q], W[(size_t)q*Np + j], s);
  if(act==1) s = fmaxf(s, 0.0f);
  C[idx] = s;
}

// feast: gather-mean over in-edges (incl self), +b, elu; optional mean (H==64)
__global__ void k_feast_gf(const float* __restrict__ Y,const int* __restrict__ offD,
                           const int* __restrict__ rowD,
                           const float* __restrict__ b,float* X,int n,int H,
                           float* __restrict__ meanacc,float inv_n){
  __shared__ float ms[4][64];
  int idx = blockIdx.x*256+threadIdx.x;
  float v = 0.0f;
  if(idx<n*H){
    int i = idx/H, h = idx - i*H;
    int p0 = offD[i], p1 = offD[i+1];
    float s = 0.0f;
    for(int p=p0;p<p1;p++) s += Y[(size_t)rowD[p]*H + h];
    float t = s/(float)(p1-p0) + b[h];
    v = t > 0.0f ? t : (expf(t)-1.0f);
    X[idx] = v;
  }
  if(meanacc){
    int r = threadIdx.x>>6, j = threadIdx.x&63;
    ms[r][j] = (idx<n*H) ? v : 0.0f;
    __syncthreads();
    if(r==0) atomicAdd(&meanacc[j], (ms[0][j]+ms[1][j]+ms[2][j]+ms[3][j])*inv_n);
  }
}

// fused sparse gconv: gather agg (real edges only), 2 matmuls, relu, mean.
__global__ __launch_bounds__(256) void k_gconv_sparse_f(
    const float* __restrict__ X,const int* __restrict__ offD,const int* __restrict__ rowD,
    const int* __restrict__ eidD,int E,
    const float* __restrict__ Wrel,const float* __restrict__ brel,
    const float* __restrict__ Wroot,
    float* __restrict__ XN,int n,float* __restrict__ meanacc,float inv_n)
{
  __shared__ float agg_s[4][65];
  __shared__ float xrow[4][65];
  __shared__ float cnt_s[4];
  const int tid = threadIdx.x;
  const int r = tid>>6, j = tid&63;
  const int i = blockIdx.x*4 + r;
  float a = 0.0f;
  if (i < n){
    int p0 = offD[i], p1 = offD[i+1], c = 0;
    for(int p=p0;p<p1;p++){
      if (eidD[p] < E){ a += X[(size_t)rowD[p]*64 + j]; c++; }
    }
    xrow[r][j] = X[(size_t)i*64 + j];
    if (j == 0) cnt_s[r] = (float)(c>1?c:1);
  }
  agg_s[r][j] = a;
  __syncthreads();
  float v = 0.0f;
  if (i < n){
    float acc=0.0f, rt=0.0f;
    for(int q=0;q<64;q++){
      acc = fmaf(agg_s[r][q], Wrel[q*64+j], acc);
      rt  = fmaf(xrow[r][q],  Wroot[q*64+j], rt);
    }
    v = fmaxf(acc/cnt_s[r] + brel[j] + rt, 0.0f);
    XN[(size_t)i*64 + j] = v;
  }
  __syncthreads();
  agg_s[r][j] = v;
  __syncthreads();
  if (r == 0) atomicAdd(&meanacc[j], (agg_s[0][j]+agg_s[1][j]+agg_s[2][j]+agg_s[3][j])*inv_n);
}

// pool0: xq = segmax gather (incl self) then @pW+pb
__global__ __launch_bounds__(256) void k_xqmaxq(
    const float* __restrict__ X,const int* __restrict__ offD,const int* __restrict__ rowD,
    const float* __restrict__ pWp,const float* __restrict__ pbp,
    float* __restrict__ XQ2,int n)
{
  __shared__ float xq[4][65];
  const int tid = threadIdx.x;
  const int r = tid>>6, j = tid&63;
  const int i = blockIdx.x*4 + r;
  float v = -3.0e38f;
  if (i < n){
    int p0 = offD[i], p1 = offD[i+1];
    for(int p=p0;p<p1;p++) v = fmaxf(v, X[(size_t)rowD[p]*64 + j]);
  }
  xq[r][j] = v;
  __syncthreads();
  if (i < n){
    float s = pbp[j];
    for(int q=0;q<64;q++) s = fmaf(xq[r][q], pWp[q*64+j], s);
    XQ2[(size_t)i*64+j] = s;
  }
}

__global__ void k_edge_score(const int* __restrict__ src,const int* __restrict__ dst,
                             const float* __restrict__ XQ2,const float* __restrict__ X,
                             float* sE,int E,int n){
  int e = blockIdx.x*256+threadIdx.x; if(e>=E+n) return;
  int s,d; edge_sd(e,src,dst,E,s,d);
  const float* q = XQ2 + (size_t)d*64;
  const float* x = X + (size_t)s*64;
  float acc = 0.0f;
  for(int h=0;h<64;h++) acc = fmaf(q[h], x[h], acc);
  sE[e] = acc > 0.0f ? acc : 0.2f*acc;
}

// per-dst softmax over in-edges -> scE
__global__ void k_dstsoft(const int* __restrict__ offD,const int* __restrict__ eidD,
                          const float* __restrict__ sE,float* __restrict__ scE,int n){
  int i = blockIdx.x*256+threadIdx.x; if(i>=n) return;
  int p0 = offD[i], p1 = offD[i+1];
  float m = -3.0e38f;
  for(int p=p0;p<p1;p++) m = fmaxf(m, sE[eidD[p]]);
  float d = 0.0f;
  for(int p=p0;p<p1;p++) d += expf(sE[eidD[p]]-m);
  float inv = 1.0f/d;
  for(int p=p0;p<p1;p++){ int e = eidD[p]; scE[e] = expf(sE[e]-m)*inv; }
}

// pool0: xc gather + aN/bN/cN; zeroes pcnt
__global__ __launch_bounds__(256) void k_xcabc0(
    const int* __restrict__ offD,const int* __restrict__ rowD,const int* __restrict__ eidD,
    const float* __restrict__ scE,const float* __restrict__ X,
    float* __restrict__ XC,
    const float* __restrict__ w1,const float* bb1,const float* __restrict__ w2,
    const float* __restrict__ w3,const float* bb3,
    float* aN,float* bN,float* cN,int* pcnt,int n)
{
  __shared__ float xc[4][65];
  const int tid = threadIdx.x;
  const int r = tid>>6, j = tid&63;
  const int i = blockIdx.x*4 + r;
  if (blockIdx.x==0 && tid==0) *pcnt = 0;
  float v = 0.0f;
  if (i < n){
    int p0 = offD[i], p1 = offD[i+1];
    for(int p=p0;p<p1;p++) v += scE[eidD[p]] * X[(size_t)rowD[p]*64 + j];
    XC[(size_t)i*64+j] = v;
  }
  xc[r][j] = v;
  __syncthreads();
  if (i < n && j < 3){
    float s = (j==0)?bb1[0]:((j==2)?bb3[0]:0.0f);
    const float* w = (j==0)?w1:((j==1)?w2:w3);
    for(int q=0;q<64;q++) s = fmaf(xc[r][q], w[q], s);
    if(j==0) aN[i]=s; else if(j==1) bN[i]=s; else cN[i]=s;
  }
}

__global__ void k_aggfit0(const int* __restrict__ offD,const int* __restrict__ rowD,
                          const float* aN,const float* bN,const float* cN,
                          float* fit,int n){
  int i = blockIdx.x*256+threadIdx.x; if(i>=n) return;
  int p0 = offD[i], p1 = offD[i+1];
  float s = 0.0f;
  for(int p=p0;p<p1;p++) s += aN[rowD[p]];
  fit[i] = sigm(s - (float)(p1-p0)*bN[i] + cN[i]);
}

__global__ void k_stage1n(const int* src,const int* dst,const int* __restrict__ offS,
                          const int* __restrict__ colS,const int* __restrict__ eidS,
                          const float* __restrict__ scE,
                          float* R,int E,int n){
  int e = blockIdx.x*256+threadIdx.x; if(e>=E+n) return;
  int i,j; edge_sd(e,src,dst,E,i,j);
  int p0 = offS[j], p1 = offS[j+1];
  float* Ri = R + (size_t)i*n;
  for(int p=p0;p<p1;p++) atomicAdd(&Ri[colS[p]], scE[eidS[p]]);
}

// gather R columns by perm: Rg[i][u] = R[i*n + perm[u]]  (row-resident in L1)
__global__ void k_gather_cols(const float* __restrict__ R,int n,const int* __restrict__ perm,
                              float* __restrict__ Rg,int kk){
  int idx = blockIdx.x*256+threadIdx.x; if(idx>=n*kk) return;
  int i = idx/kk, u = idx - i*kk;
  Rg[idx] = R[(size_t)i*n + perm[u]];
}
// A0[u][v] = sum_p scE[eid] * Rg[rowD[p]*kk + v]  (consecutive v coalesced; Rg fits L2)
__global__ void k_stage2v(const int* __restrict__ perm,const int* __restrict__ offD,
                          const int* __restrict__ rowD,const int* __restrict__ eidD,
                          const float* __restrict__ scE,
                          const float* __restrict__ Rg,float* A,int kk){
  int idx = blockIdx.x*256+threadIdx.x; if(idx>=kk*kk) return;
  int u = idx/kk, v = idx - u*kk;
  int d = perm[u];
  float acc = 0.0f;
  int p0 = offD[d], p1 = offD[d+1];
  for(int p=p0;p<p1;p++) acc = fmaf(scE[eidD[p]], Rg[(size_t)rowD[p]*kk + v], acc);
  A[idx] = (u==v) ? 0.0f : acc;
}

__global__ void k_head2(const float* __restrict__ xs,const float* __restrict__ W1,
                        const float* __restrict__ b1,const float* __restrict__ W2,
                        const float* __restrict__ b2,float* out){
  __shared__ float h2[64];
  __shared__ float lg[10];
  int t = threadIdx.x;
  float s = b1[t];
  for(int q=0;q<640;q++) s = fmaf(xs[q], W1[q*64+t], s);
  h2[t] = fmaxf(s, 0.0f);
  __syncthreads();
  if(t < 10){
    float s2 = b2[t];
    for(int k=0;k<64;k++) s2 = fmaf(h2[k], W2[k*10+t], s2);
    lg[t] = s2;
  }
  __syncthreads();
  if(t == 0){
    float mx = lg[0];
    for(int i=1;i<10;i++) mx = fmaxf(mx, lg[i]);
    float se = 0.0f;
    for(int i=0;i<10;i++) se += expf(lg[i]-mx);
    float lse = mx + logf(se);
    for(int i=0;i<10;i++) out[i] = lg[i]-lse;
  }
}

// ---------------- host orchestration ----------------
extern "C" void kernel_launch(void* const* d_in, const int* in_sizes, int n_in,
                              void* d_out, int out_size, void* d_ws, size_t ws_size,
                              hipStream_t stream) {
  const int N0 = 1500, E = 24000, Z = 16, L = E + N0;
  const float* x0   = (const float*)d_in[0];
  const int* esrc   = (const int*)d_in[1];
  const int* edst   = (const int*)d_in[2];
  const float* W1   = (const float*)d_in[3];  const float* b1   = (const float*)d_in[4];
  const float* W2   = (const float*)d_in[5];  const float* b2   = (const float*)d_in[6];
  const float* W3   = (const float*)d_in[7];  const float* b3   = (const float*)d_in[8];
  const float* Wrel = (const float*)d_in[9];  const float* brel = (const float*)d_in[10];
  const float* Wroot= (const float*)d_in[11];
  const float* pW   = (const float*)d_in[12]; const float* pb   = (const float*)d_in[13];
  const float* leW1 = (const float*)d_in[14]; const float* leb1 = (const float*)d_in[15];
  const float* leW2 = (const float*)d_in[16]; const float* leW3 = (const float*)d_in[17];
  const float* leb3 = (const float*)d_in[18];
  const float* linW1= (const float*)d_in[19]; const float* linb1= (const float*)d_in[20];
  const float* linW2= (const float*)d_in[21]; const float* linb2= (const float*)d_in[22];
  float* out = (float*)d_out;

  float* ws = (float*)d_ws;
  size_t cur = 0;
  auto allocF = [&](size_t nf)->float*{ float* p = ws + cur; cur += (nf + 15) & ~(size_t)15; return p; };
  // contiguous zero block: xs | indeg | outdeg
  float* xs   = allocF(640);
  int* indeg  = (int*)allocF(1504);
  int* outdeg = (int*)allocF(1504);
  float* Xa  = allocF(96000); float* Xb  = allocF(96000); float* Y   = allocF(96000);
  float* XQ2 = allocF(96000); float* XC  = allocF(96000);
  float* mcol = allocF(1504); float* invd = allocF(1504);
  float* aN = allocF(1504); float* bN = allocF(1504); float* cN = allocF(1504);
  float* fit = allocF(1504); float* cntP = allocF(1504);
  int* pcnt = (int*)allocF(16);
  int* perm = (int*)allocF(1504);
  int* offD = (int*)allocF(1504); int* offS = (int*)allocF(1504);
  int* curD = (int*)allocF(1504); int* curS = (int*)allocF(1504);
  int* colS = (int*)allocF(25504); int* eidS = (int*)allocF(25504);
  int* rowD = (int*)allocF(25504); int* eidD = (int*)allocF(25504);
  float* sE = allocF(25504); float* scE = allocF(25504);
  int* cntp8 = (int*)allocF((size_t)Z*1504);
  float* aggp = allocF(16*1504);
  float* SEGP = allocF((size_t)Z*1504*64);
  float* Rbig = allocF((size_t)1500*1500);   // pool0 R; aliased as SCb afterwards
  float* SCb  = Rbig;
  float* Rg   = allocF((size_t)1500*1350);   // gathered columns
  float* A0  = allocF((size_t)1350*1350);
  float* A1s = allocF((size_t)1350*1350);
  const size_t BFSZ = (size_t)1350*4224/2 + 32;
  ushort* Abf = (ushort*)allocF(BFSZ);
  ushort* Bbf = (ushort*)allocF(BFSZ);
  ushort* Cbf = (ushort*)allocF(BFSZ);
  ushort* Dbf = (ushort*)allocF(BFSZ);

  dim3 B256(256);
  auto G1 = [&](size_t n){ return dim3((unsigned)((n + 255) / 256)); };
  auto ZF = [&](void* p, size_t nfloats){ k_zero<<<G1(nfloats),B256,0,stream>>>((float*)p, nfloats); };
  auto kcz = [&](int K){ return (int)(((K + Z*16 - 1) / (Z*16)) * 16); };

  // ---- prologue: zero (xs+indeg+outdeg contiguous), degrees, CSR ----
  ZF(xs, 640 + 1504 + 1504);
  k_deg<<<G1(E),B256,0,stream>>>(esrc, edst, indeg, outdeg, E);
  k_prefix2<<<dim3((N0+256)/256,2),B256,0,stream>>>(indeg, outdeg, offD, curD, offS, curS, N0);
  k_csr_fill2<<<G1(L),B256,0,stream>>>(esrc, edst, curS, colS, eidS, curD, rowD, eidD, E, N0);

  // ---- FEAST x3 (2 nodes each) ----
  auto feast = [&](const float* xin,int cin,const float* W,const float* bb,int hh,float* xout,float* macc){
    k_mm_small<<<G1((size_t)N0*hh),B256,0,stream>>>(xin, W, nullptr, Y, N0, cin, hh, 0);
    k_feast_gf<<<G1((size_t)N0*hh),B256,0,stream>>>(Y, offD, rowD, bb, xout, N0, hh, macc, 1.0f/N0);
  };
  feast(x0, 16, W1, b1, 32, Xa, nullptr);
  feast(Xa, 32, W2, b2, 64, Xb, nullptr);
  feast(Xb, 64, W3, b3, 64, Xa, xs + 0);
  float* X = Xa; float* XN = Xb;

  // ---- i=0 gconv_sparse (1 node) ----
  k_gconv_sparse_f<<<dim3((N0+3)/4),B256,0,stream>>>(X, offD, rowD, eidD, E, Wrel, brel, Wroot,
                                                     XN, N0, xs + 64, 1.0f/N0);
  { float* t = X; X = XN; XN = t; }

  // ---- pool 0 (sparse ASAP), n=1500 -> k=1350 ----
  {
    const int n = 1500, kk = 1350;
    k_xqmaxq<<<dim3((n+3)/4),B256,0,stream>>>(X, offD, rowD, pW, pb, XQ2, n);
    k_edge_score<<<G1(L),B256,0,stream>>>(esrc, edst, XQ2, X, sE, E, n);
    k_dstsoft<<<G1(n),B256,0,stream>>>(offD, eidD, sE, scE, n);
    k_xcabc0<<<dim3((n+3)/4),B256,0,stream>>>(offD, rowD, eidD, scE, X, XC,
                                              leW1, leb1, leW2, leW3, leb3, aN, bN, cN, pcnt, n);
    k_aggfit0<<<G1(n),B256,0,stream>>>(offD, rowD, aN, bN, cN, fit, n);
    k_rank_fused<0><<<G1(n),B256,0,stream>>>(fit, nullptr, nullptr, nullptr, nullptr, nullptr,
                                             XC, XN, n, kk, pcnt, perm);
    ZF(Rbig, (size_t)n*n);
    k_stage1n<<<G1(L),B256,0,stream>>>(esrc, edst, offS, colS, eidS, scE, Rbig, E, n);
    k_gather_cols<<<G1((size_t)n*kk),B256,0,stream>>>(Rbig, n, perm, Rg, kk);
    k_stage2v<<<G1((size_t)kk*kk),B256,0,stream>>>(perm, offD, rowD, eidD, scE, Rg, A0, kk);
    { float* t = X; X = XN; XN = t; }
  }

  float* Acur = A0; float* Aoth = A1s;
  int nn = 1350;

  // ---- dense gconv (ONE node) ----
  auto gconv_dense = [&](int layer){
    k_gconv_one<<<dim3((nn+3)/4),B256,0,stream>>>(Acur, X,
        Wrel + (size_t)layer*4096, brel + layer*64, Wroot + (size_t)layer*4096,
        XN, nn, xs + (size_t)(layer+1)*64, 1.0f/nn);
    { float* t = X; X = XN; XN = t; }
  };

  // ---- dense ASAP pool ----
  auto asap_dense = [&](int kk, int p){
    {
      dim3 g(1, (nn+63)/64, Z);
      k_skinny<true,true,false,true><<<g,B256,0,stream>>>(Acur, nn, X, nullptr, SEGP, cntp8, nn, nn, kcz(nn));
    }
    k_poolq<<<dim3((nn+3)/4),B256,0,stream>>>(SEGP, cntp8, Z, pW + (size_t)p*4096, pb + p*64,
                                              X, Abf, Bbf, cntP, nn);
    {
      dim3 g((nn+63)/64, (nn+63)/64);
      k_gemm_mfma<1><<<g,B256,0,stream>>>(Abf, Bbf, SCb, nn, nn, nn, 192, Acur, nn);
    }
    k_smax_fused<<<dim3((nn+15)/16),B256,0,stream>>>(SCb, nn, mcol, invd);
    {
      dim3 g(1, (nn+63)/64, Z);
      k_skinny<false,false,true,false><<<g,B256,0,stream>>>(SCb, nn, X, mcol, SEGP, nullptr, nn, nn, kcz(nn));
    }
    k_xcabc_dense<<<dim3((nn+3)/4),B256,0,stream>>>(SEGP, Z, invd, XC,
        leW1 + p*64, leb1 + p, leW2 + p*64, leW3 + p*64, leb3 + p, aN, bN, cN, pcnt, nn);
    k_aggcol<<<G1((size_t)nn*16),B256,0,stream>>>(Acur, aN, aggp, nn);
    k_rank_fused<1><<<G1(nn),B256,0,stream>>>(nullptr, aggp, cntP, aN, bN, cN,
                                              XC, XN, nn, kk, pcnt, perm);
    const int Kp = (nn + 63) & ~63;
    const int K3 = 3*Kp;
    k_split3<<<G1((size_t)nn*Kp),B256,0,stream>>>(Acur, nn, nn, nn, Abf, Kp, 0);
    { dim3 gt((kk+31)/32, Kp/32);
      k_split3_Tdual<<<gt,B256,0,stream>>>(SCb, nn, kk, nn, perm, invd, mcol, Dbf, Bbf, Cbf, Kp); }
    { dim3 g((kk+63)/64, (nn+63)/64);
      k_gemm_mfma_tb<<<g,B256,0,stream>>>(Abf, Bbf, Cbf, Kp, nn, kk, K3); }
    { dim3 g((kk+63)/64, (kk+63)/64);
      k_gemm_mfma<2><<<g,B256,0,stream>>>(Dbf, Cbf, Aoth, kk, kk, kk, K3, nullptr, 0); }
    { float* t = X; X = XN; XN = t; }
    { float* t = Acur; Acur = Aoth; Aoth = t; }
    nn = kk;
  };

  gconv_dense(1);
  gconv_dense(2);
  asap_dense(1215, 1);
  gconv_dense(3);
  gconv_dense(4);
  asap_dense(1094, 2);
  gconv_dense(5);
  gconv_dense(6);
  asap_dense(985, 3);
  gconv_dense(7);
  gconv_dense(8);

  // ---- head (1 node) ----
  k_head2<<<1,64,0,stream>>>(xs, linW1, linb1, linW2, linb2, out);
}

// Round 14
// 1507.833 us; speedup vs baseline: 1.3916x; 1.3916x over previous
//
#include <hip/hip_runtime.h>
#include <math.h>

#define NEGV -1000000000.0f

typedef short short8 __attribute__((ext_vector_type(8)));
typedef float floatx4 __attribute__((ext_vector_type(4)));

__device__ __forceinline__ float sigm(float x){ return 1.0f/(1.0f+expf(-x)); }
__device__ __forceinline__ void edge_sd(int e,const int* src,const int* dst,int E,int& s,int& d){
  if(e<E){ s=src[e]; d=dst[e]; } else { s=e-E; d=s; }
}
__device__ __forceinline__ ushort bf16rn(float x){
  unsigned u = __float_as_uint(x);
  unsigned r = (u + 0x7fffu + ((u>>16)&1u)) >> 16;
  return (ushort)r;
}
__device__ __forceinline__ float bf16f(ushort h){ return __uint_as_float(((unsigned)h)<<16); }

__global__ void k_zero(float* __restrict__ p, size_t n){
  size_t i = (size_t)blockIdx.x*256 + threadIdx.x;
  if (i < n) p[i] = 0.0f;
}

// ---------------- bf16x3 conversions ----------------
__global__ void k_split3(const float* __restrict__ src,int R,int Cs,int ld,
                         ushort* __restrict__ dst,int Cp,int bmode){
  int idx = blockIdx.x*256+threadIdx.x;
  if (idx >= R*Cp) return;
  int r = idx / Cp, c = idx - r*Cp;
  float x = (c < Cs) ? src[(size_t)r*ld + c] : 0.0f;
  ushort h = bf16rn(x);
  ushort l = bf16rn(x - bf16f(h));
  size_t base = (size_t)r*(3*Cp) + c;
  dst[base]        = h;
  dst[base + Cp]   = bmode ? l : h;
  dst[base + 2*Cp] = bmode ? h : l;
}
// Sp = exp(src[:,perm]-mcol[perm])*invd[perm], transposed to K-innermost; writes BOTH
// A-role (dstA) and B-role (dstB); zero-pads k>=Rs rows in dstA/dstB AND dstCpad.
__global__ void k_split3_Tdual(const float* __restrict__ src,int Rs,int Cs,int ld,
                               const int* __restrict__ gperm,const float* __restrict__ cscale,
                               const float* __restrict__ emax,
                               ushort* __restrict__ dstA,ushort* __restrict__ dstB,
                               ushort* __restrict__ dstCpad,int Kp){
  __shared__ float t[32][33];
  int tx = threadIdx.x & 31, ty = threadIdx.x >> 5;
  int kb = blockIdx.y*32, xb = blockIdx.x*32;
  int x = xb + tx;
  int gx = (x < Cs) ? gperm[x] : 0;
#pragma unroll
  for (int i=0;i<4;i++){
    int k = kb + ty + i*8;
    t[ty+i*8][tx] = (k < Rs && x < Cs) ? src[(size_t)k*ld + gx] : 0.0f;
  }
  __syncthreads();
  const int K3 = 3*Kp;
#pragma unroll
  for (int i=0;i<4;i++){
    int xo = xb + ty + i*8, ko = kb + tx;
    if (xo < Cs){
      float v = 0.0f;
      if (ko < Rs){
        int g = gperm[xo];
        v = expf(t[tx][ty+i*8] - emax[g]) * cscale[g];
      }
      ushort h = bf16rn(v);
      ushort l = bf16rn(v - bf16f(h));
      size_t base = (size_t)xo*K3 + ko;
      dstA[base] = h; dstA[base+Kp] = h; dstA[base+2*Kp] = l;
      dstB[base] = h; dstB[base+Kp] = l; dstB[base+2*Kp] = h;
      if (ko >= Rs){ dstCpad[base]=0; dstCpad[base+Kp]=0; dstCpad[base+2*Kp]=0; }
    }
  }
}

// ---------------- MFMA bf16 GEMM (64x64 tile, K-step 64, double-buffered) ----------------
// EPI 1: mask(A+I)+leakyrelu; EPI 2: zero diag.
template<int EPI>
__global__ __launch_bounds__(256) void k_gemm_mfma(
    const ushort* __restrict__ A, const ushort* __restrict__ B,
    float* __restrict__ C, int ldc, int M, int N, int K3,
    const float* __restrict__ mask, int ldm)
{
  __shared__ ushort As[2][64][72];
  __shared__ ushort Bs[2][64][72];
  const int tid = threadIdx.x;
  const int m0 = blockIdx.y*64, n0 = blockIdx.x*64;
  const int w = tid>>6, lane = tid&63;
  const int lo4 = lane&15, quad = lane>>4;
  const int sr = tid>>2, sseg = tid&3;

  floatx4 acc[4];
#pragma unroll
  for(int c=0;c<4;c++){ acc[c][0]=0.f; acc[c][1]=0.f; acc[c][2]=0.f; acc[c][3]=0.f; }

  const size_t arow = (size_t)(m0+sr)*K3;
  const size_t brow = (size_t)(n0+sr)*K3;
  const bool aval = (m0+sr) < M;
  const bool bval = (n0+sr) < N;

  uint4 av0 = make_uint4(0,0,0,0), av1 = make_uint4(0,0,0,0);
  uint4 bv0 = make_uint4(0,0,0,0), bv1 = make_uint4(0,0,0,0);
  if (aval){ av0 = *(const uint4*)(A + arow + sseg*8);
             av1 = *(const uint4*)(A + arow + 32 + sseg*8); }
  if (bval){ bv0 = *(const uint4*)(B + brow + sseg*8);
             bv1 = *(const uint4*)(B + brow + 32 + sseg*8); }
  *(uint4*)&As[0][sr][sseg*8] = av0; *(uint4*)&As[0][sr][32+sseg*8] = av1;
  *(uint4*)&Bs[0][sr][sseg*8] = bv0; *(uint4*)&Bs[0][sr][32+sseg*8] = bv1;
  __syncthreads();

  const int T = K3 >> 6;
  for (int i=0;i<T;i++){
    const int cb = i & 1;
    if (i+1 < T){
      const int k0 = (i+1)<<6;
      av0 = make_uint4(0,0,0,0); av1 = make_uint4(0,0,0,0);
      bv0 = make_uint4(0,0,0,0); bv1 = make_uint4(0,0,0,0);
      if (aval){ av0 = *(const uint4*)(A + arow + k0 + sseg*8);
                 av1 = *(const uint4*)(A + arow + k0 + 32 + sseg*8); }
      if (bval){ bv0 = *(const uint4*)(B + brow + k0 + sseg*8);
                 bv1 = *(const uint4*)(B + brow + k0 + 32 + sseg*8); }
    }
    short8 af0 = *(const short8*)&As[cb][16*w + lo4][quad*8];
    short8 af1 = *(const short8*)&As[cb][16*w + lo4][32+quad*8];
#pragma unroll
    for (int c=0;c<4;c++){
      short8 bf0 = *(const short8*)&Bs[cb][16*c + lo4][quad*8];
      acc[c] = __builtin_amdgcn_mfma_f32_16x16x32_bf16(af0, bf0, acc[c], 0, 0, 0);
      short8 bf1 = *(const short8*)&Bs[cb][16*c + lo4][32+quad*8];
      acc[c] = __builtin_amdgcn_mfma_f32_16x16x32_bf16(af1, bf1, acc[c], 0, 0, 0);
    }
    if (i+1 < T){
      __syncthreads();
      *(uint4*)&As[1-cb][sr][sseg*8] = av0; *(uint4*)&As[1-cb][sr][32+sseg*8] = av1;
      *(uint4*)&Bs[1-cb][sr][sseg*8] = bv0; *(uint4*)&Bs[1-cb][sr][32+sseg*8] = bv1;
      __syncthreads();
    }
  }

#pragma unroll
  for (int c=0;c<4;c++){
    const int gn = n0 + 16*c + lo4;
#pragma unroll
    for (int r=0;r<4;r++){
      const int gm = m0 + 16*w + quad*4 + r;
      if (gm < M && gn < N){
        float v = acc[c][r];
        if (EPI==1) v = (mask[(size_t)gm*ldm+gn] != 0.0f || gm==gn) ? (v > 0.0f ? v : 0.2f*v) : NEGV;
        if (EPI==2 && gm==gn) v = 0.0f;
        C[(size_t)gm*ldc+gn] = v;
      }
    }
  }
}

// TB = A@Sp + Sp (fp32 acc), double-buffered; output written directly as bf16x3
// B-role TRANSPOSED. Sp re-read from its B-role bf16x3 (h+l) at the output addresses.
__global__ __launch_bounds__(256) void k_gemm_mfma_tb(
    const ushort* __restrict__ A, const ushort* __restrict__ B,
    ushort* __restrict__ Cb, int Kp, int M, int N, int K3)
{
  __shared__ ushort As[2][64][72];
  __shared__ ushort Bs[2][64][72];
  const int tid = threadIdx.x;
  const int m0 = blockIdx.y*64, n0 = blockIdx.x*64;
  const int w = tid>>6, lane = tid&63;
  const int lo4 = lane&15, quad = lane>>4;
  const int sr = tid>>2, sseg = tid&3;

  floatx4 acc[4];
#pragma unroll
  for(int c=0;c<4;c++){ acc[c][0]=0.f; acc[c][1]=0.f; acc[c][2]=0.f; acc[c][3]=0.f; }

  const size_t arow = (size_t)(m0+sr)*K3;
  const size_t brow = (size_t)(n0+sr)*K3;
  const bool aval = (m0+sr) < M;
  const bool bval = (n0+sr) < N;

  uint4 av0 = make_uint4(0,0,0,0), av1 = make_uint4(0,0,0,0);
  uint4 bv0 = make_uint4(0,0,0,0), bv1 = make_uint4(0,0,0,0);
  if (aval){ av0 = *(const uint4*)(A + arow + sseg*8);
             av1 = *(const uint4*)(A + arow + 32 + sseg*8); }
  if (bval){ bv0 = *(const uint4*)(B + brow + sseg*8);
             bv1 = *(const uint4*)(B + brow + 32 + sseg*8); }
  *(uint4*)&As[0][sr][sseg*8] = av0; *(uint4*)&As[0][sr][32+sseg*8] = av1;
  *(uint4*)&Bs[0][sr][sseg*8] = bv0; *(uint4*)&Bs[0][sr][32+sseg*8] = bv1;
  __syncthreads();

  const int T = K3 >> 6;
  for (int i=0;i<T;i++){
    const int cb = i & 1;
    if (i+1 < T){
      const int k0 = (i+1)<<6;
      av0 = make_uint4(0,0,0,0); av1 = make_uint4(0,0,0,0);
      bv0 = make_uint4(0,0,0,0); bv1 = make_uint4(0,0,0,0);
      if (aval){ av0 = *(const uint4*)(A + arow + k0 + sseg*8);
                 av1 = *(const uint4*)(A + arow + k0 + 32 + sseg*8); }
      if (bval){ bv0 = *(const uint4*)(B + brow + k0 + sseg*8);
                 bv1 = *(const uint4*)(B + brow + k0 + 32 + sseg*8); }
    }
    short8 af0 = *(const short8*)&As[cb][16*w + lo4][quad*8];
    short8 af1 = *(const short8*)&As[cb][16*w + lo4][32+quad*8];
#pragma unroll
    for (int c=0;c<4;c++){
      short8 bf0 = *(const short8*)&Bs[cb][16*c + lo4][quad*8];
      acc[c] = __builtin_amdgcn_mfma_f32_16x16x32_bf16(af0, bf0, acc[c], 0, 0, 0);
      short8 bf1 = *(const short8*)&Bs[cb][16*c + lo4][32+quad*8];
      acc[c] = __builtin_amdgcn_mfma_f32_16x16x32_bf16(af1, bf1, acc[c], 0, 0, 0);
    }
    if (i+1 < T){
      __syncthreads();
      *(uint4*)&As[1-cb][sr][sseg*8] = av0; *(uint4*)&As[1-cb][sr][32+sseg*8] = av1;
      *(uint4*)&Bs[1-cb][sr][sseg*8] = bv0; *(uint4*)&Bs[1-cb][sr][32+sseg*8] = bv1;
      __syncthreads();
    }
  }

  const int K3o = 3*Kp;
#pragma unroll
  for (int c=0;c<4;c++){
    const int gn = n0 + 16*c + lo4;
    if (gn < N){
#pragma unroll
      for (int r=0;r<4;r++){
        const int gm = m0 + 16*w + quad*4 + r;
        if (gm < M){
          size_t base = (size_t)gn*K3o + gm;
          float sp = bf16f(B[base]) + bf16f(B[base+Kp]);   // Sp at (gm,gn)
          float v = acc[c][r] + sp;
          ushort h = bf16rn(v);
          ushort l = bf16rn(v - bf16f(h));
          Cb[base] = h; Cb[base+Kp] = l; Cb[base+2*Kp] = h;
        }
      }
    }
  }
}

// ---------------- atomic-free skinny agg GEMM ----------------
template<bool MAXM, bool COUNT, bool EXPM, bool SELF>
__global__ __launch_bounds__(256) void k_skinny(
    const float* __restrict__ A, int lda,
    const float* __restrict__ X,
    const float* __restrict__ mcol,
    float* __restrict__ P, int* __restrict__ cntp,
    int M, int K, int kchunk)
{
  __shared__ float As[16][68];
  __shared__ float Xs[16][68];
  const int tid = threadIdx.x;
  const int m0 = blockIdx.y * 64;
  const int tmb = (tid & 15) * 4, tnb = (tid >> 4) * 4;
  float acc[4][4];
  int cacc[4] = {0,0,0,0};
#pragma unroll
  for (int i=0;i<4;i++)
#pragma unroll
    for (int j=0;j<4;j++) acc[i][j] = MAXM ? NEGV : 0.0f;

  const int kstart = blockIdx.z * kchunk;
  int kend = kstart + kchunk; if (kend > K) kend = K;
  const int ml = tid & 63, tb = tid >> 6;
  const bool mvalid = (m0 + ml) < M;
  float mc = 0.0f;
  if (EXPM && mvalid) mc = mcol[m0 + ml];

  for (int k0 = kstart; k0 < kend; k0 += 16) {
#pragma unroll
    for (int s=0;s<4;s++) {
      const int tk = tb + s*4;
      float va = 0.0f, vx = 0.0f;
      if ((k0+tk) < K) {
        if (mvalid){
          va = A[(size_t)(k0+tk)*lda + m0 + ml];
          if (EXPM) va = expf(va - mc);
        }
        vx = X[(size_t)(k0+tk)*64 + ml];
      }
      As[tk][ml] = va;
      Xs[tk][ml] = vx;
    }
    __syncthreads();
#pragma unroll
    for (int kk=0; kk<16; kk++) {
      const float4 a4 = *(const float4*)&As[kk][tmb];
      const float4 b4 = *(const float4*)&Xs[kk][tnb];
      const float av[4] = {a4.x,a4.y,a4.z,a4.w};
      const float bv[4] = {b4.x,b4.y,b4.z,b4.w};
#pragma unroll
      for (int i=0;i<4;i++){
        if (COUNT) cacc[i] += (av[i] != 0.0f) ? 1 : 0;
#pragma unroll
        for (int j=0;j<4;j++) {
          if (MAXM) acc[i][j] = fmaxf(acc[i][j], av[i] != 0.0f ? bv[j] : NEGV);
          else      acc[i][j] = fmaf(av[i], bv[j], acc[i][j]);
        }
      }
    }
    __syncthreads();
  }

  const size_t slab = (size_t)blockIdx.z * M * 64;
#pragma unroll
  for (int i=0;i<4;i++){
    const int m = m0 + tmb + i;
    if (m < M){
#pragma unroll
      for (int j=0;j<4;j++){
        float v = acc[i][j];
        if (SELF) v = fmaxf(v, X[(size_t)m*64 + tnb + j]);
        P[slab + (size_t)m*64 + tnb + j] = v;
      }
    }
  }
  if (COUNT && tnb == 0){
#pragma unroll
    for (int i=0;i<4;i++){
      const int m = m0 + tmb + i;
      if (m < M) cntp[blockIdx.z*M + m] = cacc[i];
    }
  }
}

// slab max-reduce -> xq; xq2 = xq@pW+pb; cntP = 1 + sum counts.
// Also emits bf16x3 operands: dstA (A-role from X), dstB (B-role from xq2).
__global__ __launch_bounds__(256) void k_poolq(
    const float* __restrict__ SEGP,const int* __restrict__ cntp8,int Z,
    const float* __restrict__ pWp,const float* __restrict__ pbp,
    const float* __restrict__ X,
    ushort* __restrict__ dstA,ushort* __restrict__ dstB,
    float* __restrict__ cntP,int n)
{
  __shared__ float xq[4][65];
  const int tid = threadIdx.x;
  const int r = tid>>6, j = tid&63;
  const int i = blockIdx.x*4 + r;
  float v = NEGV;
  if (i < n){
    for(int z=0;z<Z;z++) v = fmaxf(v, SEGP[(size_t)z*n*64 + (size_t)i*64 + j]);
    if (j == 0){
      int c=1; for(int z=0;z<Z;z++) c += cntp8[z*n+i];
      cntP[i] = (float)c;
    }
  }
  xq[r][j] = v;
  __syncthreads();
  if (i < n){
    float s = pbp[j];
    for(int q=0;q<64;q++) s = fmaf(xq[r][q], pWp[q*64+j], s);
    size_t base = (size_t)i*192 + j;
    ushort h = bf16rn(s), l = bf16rn(s - bf16f(h));
    dstB[base] = h; dstB[base+64] = l; dstB[base+128] = h;
    float x = X[(size_t)i*64 + j];
    h = bf16rn(x); l = bf16rn(x - bf16f(h));
    dstA[base] = h; dstA[base+64] = h; dstA[base+128] = l;
  }
}

// fused dense gconv: reduce slabs, two 64x64 matmuls, relu, mean-accumulate.
__global__ __launch_bounds__(256) void k_gconv_fuse(
    const float* __restrict__ SEGP,const int* __restrict__ cntp8,int Z,
    const float* __restrict__ Wrel,const float* __restrict__ brel,
    const float* __restrict__ X,const float* __restrict__ Wroot,
    float* __restrict__ XN,int n,float* __restrict__ meanacc,float inv_n)
{
  __shared__ float agg_s[4][65];
  __shared__ float xrow[4][65];
  __shared__ float cnt_s[4];
  const int tid = threadIdx.x;
  const int r = tid>>6, j = tid&63;
  const int i = blockIdx.x*4 + r;
  float a = 0.0f;
  if (i < n){
    for(int z=0;z<Z;z++) a += SEGP[(size_t)z*n*64 + (size_t)i*64 + j];
    xrow[r][j] = X[(size_t)i*64 + j];
    if (j == 0){
      int c=0; for(int z=0;z<Z;z++) c += cntp8[z*n+i];
      cnt_s[r] = (float)(c>1?c:1);
    }
  }
  agg_s[r][j] = a;
  __syncthreads();
  float v = 0.0f;
  if (i < n){
    float acc=0.0f, rt=0.0f;
    for(int q=0;q<64;q++){
      acc = fmaf(agg_s[r][q], Wrel[q*64+j], acc);
      rt  = fmaf(xrow[r][q],  Wroot[q*64+j], rt);
    }
    v = fmaxf(acc/cnt_s[r] + brel[j] + rt, 0.0f);
    XN[(size_t)i*64 + j] = v;
  }
  __syncthreads();
  agg_s[r][j] = v;
  __syncthreads();
  if (r == 0) atomicAdd(&meanacc[j], (agg_s[0][j]+agg_s[1][j]+agg_s[2][j]+agg_s[3][j])*inv_n);
}

// ---------------- fused column softmax stats (ONE kernel) ----------------
__global__ __launch_bounds__(256) void k_smax_fused(const float* __restrict__ S,int n,
                                                    float* __restrict__ mcol,float* __restrict__ invd){
  __shared__ float red[16][17];
  const int jc = threadIdx.x & 15, rg = threadIdx.x >> 4;
  const int j = blockIdx.x*16 + jc;
  float m = -3.0e38f;
  if (j < n)
    for(int i=rg;i<n;i+=16) m = fmaxf(m, S[(size_t)i*n+j]);
  red[rg][jc] = m;
  __syncthreads();
  for(int s=8;s>0;s>>=1){
    if(rg<s) red[rg][jc] = fmaxf(red[rg][jc], red[rg+s][jc]);
    __syncthreads();
  }
  const float mc = red[0][jc];
  __syncthreads();
  float sum = 0.0f;
  if (j < n)
    for(int i=rg;i<n;i+=16) sum += expf(S[(size_t)i*n+j]-mc);
  red[rg][jc] = sum;
  __syncthreads();
  for(int s=8;s>0;s>>=1){
    if(rg<s) red[rg][jc] += red[rg+s][jc];
    __syncthreads();
  }
  if(rg==0 && j<n){ mcol[j]=mc; invd[j]=1.0f/red[0][jc]; }
}

// slab sum * invd -> XC; then aN/bN/cN per row; zeroes pcnt.
__global__ __launch_bounds__(256) void k_xcabc_dense(
    const float* __restrict__ SEGP,int Z,const float* __restrict__ invd,
    float* __restrict__ XC,
    const float* __restrict__ w1,const float* bb1,const float* __restrict__ w2,
    const float* __restrict__ w3,const float* bb3,
    float* aN,float* bN,float* cN,int* pcnt,int n)
{
  __shared__ float xc[4][65];
  const int tid = threadIdx.x;
  const int r = tid>>6, j = tid&63;
  const int i = blockIdx.x*4 + r;
  if (blockIdx.x==0 && tid==0) *pcnt = 0;
  float v = 0.0f;
  if (i < n){
    for(int z=0;z<Z;z++) v += SEGP[(size_t)z*n*64 + (size_t)i*64 + j];
    v *= invd[i];
    XC[(size_t)i*64+j] = v;
  }
  xc[r][j] = v;
  __syncthreads();
  if (i < n && j < 3){
    float s = (j==0)?bb1[0]:((j==2)?bb3[0]:0.0f);
    const float* w = (j==0)?w1:((j==1)?w2:w3);
    for(int q=0;q<64;q++) s = fmaf(xc[r][q], w[q], s);
    if(j==0) aN[i]=s; else if(j==1) bN[i]=s; else cN[i]=s;
  }
}

__global__ void k_aggcol(const float* __restrict__ A,const float* __restrict__ aN,
                         float* __restrict__ aggp,int n){
  int idx = blockIdx.x*256+threadIdx.x; if(idx>=n*16) return;
  int j = idx % n, c = idx / n;
  int i0 = (int)(((long long)n*c)/16), i1 = (int)(((long long)n*(c+1))/16);
  float s = 0.0f;
  for(int i=i0;i<i1;i++) if(A[(size_t)i*n + j] != 0.0f) s += aN[i];
  aggp[c*n + j] = s;
}

// fit (MODE 1: from aggp slabs; MODE 0: given) + rank + perm slot + XN write, one kernel.
template<int MODE>
__global__ __launch_bounds__(256) void k_rank_fused(
    const float* __restrict__ fit_in,
    const float* __restrict__ aggp,const float* __restrict__ cntP,
    const float* __restrict__ aN,const float* __restrict__ bN,const float* __restrict__ cN,
    const float* __restrict__ XC,float* __restrict__ XN,
    int n,int k,int* pcnt,int* perm)
{
  __shared__ float fs[1504];
  const int tid = threadIdx.x;
  for(int u=tid; u<n; u+=256){
    float f;
    if (MODE==0) f = fit_in[u];
    else {
      float a = aN[u];
      for(int c=0;c<16;c++) a += aggp[c*n+u];
      f = sigm(a - cntP[u]*bN[u] + cN[u]);
    }
    fs[u] = f;
  }
  __syncthreads();
  const int v = blockIdx.x*256+tid; if(v>=n) return;
  const float fv = fs[v]; int r = 0;
  for(int u=0;u<n;u++){ float fu = fs[u]; r += (fu > fv || (fu == fv && u < v)) ? 1 : 0; }
  if (r < k){
    int p = atomicAdd(pcnt,1);
    perm[p] = v;
    const float* src = XC + (size_t)v*64;
    float* d = XN + (size_t)p*64;
    for(int h=0;h<64;h++) d[h] = src[h]*fv;
  }
}

// ---------------- prologue: degrees + CSR over L=E+n edges (incl self) ----------------
__global__ void k_deg(const int* __restrict__ src,const int* __restrict__ dst,int* indeg,int* outdeg,int E){
  int e = blockIdx.x*256+threadIdx.x; if(e>=E) return;
  atomicAdd(&indeg[dst[e]],1); atomicAdd(&outdeg[src[e]],1);
}
__global__ __launch_bounds__(256) void k_prefix2(const int* __restrict__ indeg,const int* __restrict__ outdeg,
                          int* offD,int* curD,int* offS,int* curS,int n){
  __shared__ int ds[1504];
  const int* dsrc = blockIdx.y ? outdeg : indeg;
  for(int u=threadIdx.x; u<n; u+=256) ds[u] = dsrc[u];
  __syncthreads();
  int t = blockIdx.x*256+threadIdx.x; if(t>n) return;
  int s = 0;
  for(int u=0;u<t;u++) s += ds[u]+1;
  if (blockIdx.y){ offS[t]=s; if(t<n) curS[t]=s; }
  else           { offD[t]=s; if(t<n) curD[t]=s; }
}
__global__ void k_csr_fill2(const int* src,const int* dst,
                            int* curS,int* colS,int* eidS,
                            int* curD,int* rowD,int* eidD,int E,int n){
  int e = blockIdx.x*256+threadIdx.x; if(e>=E+n) return;
  int s,d; edge_sd(e,src,dst,E,s,d);
  int p = atomicAdd(&curS[s],1); colS[p]=d; eidS[p]=e;
  int q = atomicAdd(&curD[d],1); rowD[q]=s; eidD[q]=e;
}

__global__ void k_mm_small(const float* __restrict__ A,const float* __restrict__ W,
                           const float* __restrict__ b,float* __restrict__ C,
                           int M,int K,int Np,int act){
  int idx = blockIdx.x*256+threadIdx.x; if(idx>=M*Np) return;
  int m = idx/Np, j = idx - m*Np;
  float s = b ? b[j] : 0.0f;
  const float* a = A + (size_t)m*K;
  for(int q=0;q<K;q++) s = fmaf(a[q], W[(size_t)q*Np + j], s);
  if(act==1) s = fmaxf(s, 0.0f);
  C[idx] = s;
}

// feast: gather-mean over in-edges (incl self), +b, elu; optional mean (H==64)
__global__ void k_feast_gf(const float* __restrict__ Y,const int* __restrict__ offD,
                           const int* __restrict__ rowD,
                           const float* __restrict__ b,float* X,int n,int H,
                           float* __restrict__ meanacc,float inv_n){
  __shared__ float ms[4][64];
  int idx = blockIdx.x*256+threadIdx.x;
  float v = 0.0f;
  if(idx<n*H){
    int i = idx/H, h = idx - i*H;
    int p0 = offD[i], p1 = offD[i+1];
    float s = 0.0f;
    for(int p=p0;p<p1;p++) s += Y[(size_t)rowD[p]*H + h];
    float t = s/(float)(p1-p0) + b[h];
    v = t > 0.0f ? t : (expf(t)-1.0f);
    X[idx] = v;
  }
  if(meanacc){
    int r = threadIdx.x>>6, j = threadIdx.x&63;
    ms[r][j] = (idx<n*H) ? v : 0.0f;
    __syncthreads();
    if(r==0) atomicAdd(&meanacc[j], (ms[0][j]+ms[1][j]+ms[2][j]+ms[3][j])*inv_n);
  }
}

// fused sparse gconv: gather agg (real edges only), 2 matmuls, relu, mean.
__global__ __launch_bounds__(256) void k_gconv_sparse_f(
    const float* __restrict__ X,const int* __restrict__ offD,const int* __restrict__ rowD,
    const int* __restrict__ eidD,int E,
    const float* __restrict__ Wrel,const float* __restrict__ brel,
    const float* __restrict__ Wroot,
    float* __restrict__ XN,int n,float* __restrict__ meanacc,float inv_n)
{
  __shared__ float agg_s[4][65];
  __shared__ float xrow[4][65];
  __shared__ float cnt_s[4];
  const int tid = threadIdx.x;
  const int r = tid>>6, j = tid&63;
  const int i = blockIdx.x*4 + r;
  float a = 0.0f;
  if (i < n){
    int p0 = offD[i], p1 = offD[i+1], c = 0;
    for(int p=p0;p<p1;p++){
      if (eidD[p] < E){ a += X[(size_t)rowD[p]*64 + j]; c++; }
    }
    xrow[r][j] = X[(size_t)i*64 + j];
    if (j == 0) cnt_s[r] = (float)(c>1?c:1);
  }
  agg_s[r][j] = a;
  __syncthreads();
  float v = 0.0f;
  if (i < n){
    float acc=0.0f, rt=0.0f;
    for(int q=0;q<64;q++){
      acc = fmaf(agg_s[r][q], Wrel[q*64+j], acc);
      rt  = fmaf(xrow[r][q],  Wroot[q*64+j], rt);
    }
    v = fmaxf(acc/cnt_s[r] + brel[j] + rt, 0.0f);
    XN[(size_t)i*64 + j] = v;
  }
  __syncthreads();
  agg_s[r][j] = v;
  __syncthreads();
  if (r == 0) atomicAdd(&meanacc[j], (agg_s[0][j]+agg_s[1][j]+agg_s[2][j]+agg_s[3][j])*inv_n);
}

// pool0: xq = segmax gather (incl self) then @pW+pb
__global__ __launch_bounds__(256) void k_xqmaxq(
    const float* __restrict__ X,const int* __restrict__ offD,const int* __restrict__ rowD,
    const float* __restrict__ pWp,const float* __restrict__ pbp,
    float* __restrict__ XQ2,int n)
{
  __shared__ float xq[4][65];
  const int tid = threadIdx.x;
  const int r = tid>>6, j = tid&63;
  const int i = blockIdx.x*4 + r;
  float v = -3.0e38f;
  if (i < n){
    int p0 = offD[i], p1 = offD[i+1];
    for(int p=p0;p<p1;p++) v = fmaxf(v, X[(size_t)rowD[p]*64 + j]);
  }
  xq[r][j] = v;
  __syncthreads();
  if (i < n){
    float s = pbp[j];
    for(int q=0;q<64;q++) s = fmaf(xq[r][q], pWp[q*64+j], s);
    XQ2[(size_t)i*64+j] = s;
  }
}

__global__ void k_edge_score(const int* __restrict__ src,const int* __restrict__ dst,
                             const float* __restrict__ XQ2,const float* __restrict__ X,
                             float* sE,int E,int n){
  int e = blockIdx.x*256+threadIdx.x; if(e>=E+n) return;
  int s,d; edge_sd(e,src,dst,E,s,d);
  const float* q = XQ2 + (size_t)d*64;
  const float* x = X + (size_t)s*64;
  float acc = 0.0f;
  for(int h=0;h<64;h++) acc = fmaf(q[h], x[h], acc);
  sE[e] = acc > 0.0f ? acc : 0.2f*acc;
}

// per-dst softmax over in-edges -> scE
__global__ void k_dstsoft(const int* __restrict__ offD,const int* __restrict__ eidD,
                          const float* __restrict__ sE,float* __restrict__ scE,int n){
  int i = blockIdx.x*256+threadIdx.x; if(i>=n) return;
  int p0 = offD[i], p1 = offD[i+1];
  float m = -3.0e38f;
  for(int p=p0;p<p1;p++) m = fmaxf(m, sE[eidD[p]]);
  float d = 0.0f;
  for(int p=p0;p<p1;p++) d += expf(sE[eidD[p]]-m);
  float inv = 1.0f/d;
  for(int p=p0;p<p1;p++){ int e = eidD[p]; scE[e] = expf(sE[e]-m)*inv; }
}

// pool0: xc gather + aN/bN/cN; zeroes pcnt
__global__ __launch_bounds__(256) void k_xcabc0(
    const int* __restrict__ offD,const int* __restrict__ rowD,const int* __restrict__ eidD,
    const float* __restrict__ scE,const float* __restrict__ X,
    float* __restrict__ XC,
    const float* __restrict__ w1,const float* bb1,const float* __restrict__ w2,
    const float* __restrict__ w3,const float* bb3,
    float* aN,float* bN,float* cN,int* pcnt,int n)
{
  __shared__ float xc[4][65];
  const int tid = threadIdx.x;
  const int r = tid>>6, j = tid&63;
  const int i = blockIdx.x*4 + r;
  if (blockIdx.x==0 && tid==0) *pcnt = 0;
  float v = 0.0f;
  if (i < n){
    int p0 = offD[i], p1 = offD[i+1];
    for(int p=p0;p<p1;p++) v += scE[eidD[p]] * X[(size_t)rowD[p]*64 + j];
    XC[(size_t)i*64+j] = v;
  }
  xc[r][j] = v;
  __syncthreads();
  if (i < n && j < 3){
    float s = (j==0)?bb1[0]:((j==2)?bb3[0]:0.0f);
    const float* w = (j==0)?w1:((j==1)?w2:w3);
    for(int q=0;q<64;q++) s = fmaf(xc[r][q], w[q], s);
    if(j==0) aN[i]=s; else if(j==1) bN[i]=s; else cN[i]=s;
  }
}

__global__ void k_aggfit0(const int* __restrict__ offD,const int* __restrict__ rowD,
                          const float* aN,const float* bN,const float* cN,
                          float* fit,int n){
  int i = blockIdx.x*256+threadIdx.x; if(i>=n) return;
  int p0 = offD[i], p1 = offD[i+1];
  float s = 0.0f;
  for(int p=p0;p<p1;p++) s += aN[rowD[p]];
  fit[i] = sigm(s - (float)(p1-p0)*bN[i] + cN[i]);
}

__global__ void k_stage1n(const int* src,const int* dst,const int* __restrict__ offS,
                          const int* __restrict__ colS,const int* __restrict__ eidS,
                          const float* __restrict__ scE,
                          float* R,int E,int n){
  int e = blockIdx.x*256+threadIdx.x; if(e>=E+n) return;
  int i,j; edge_sd(e,src,dst,E,i,j);
  int p0 = offS[j], p1 = offS[j+1];
  float* Ri = R + (size_t)i*n;
  for(int p=p0;p<p1;p++) atomicAdd(&Ri[colS[p]], scE[eidS[p]]);
}
__global__ void k_stage2p(const int* __restrict__ perm,const int* __restrict__ offD,
                          const int* __restrict__ rowD,const int* __restrict__ eidD,
                          const float* __restrict__ scE,
                          const float* __restrict__ R,float* A,int k,int n){
  int idx = blockIdx.x*256+threadIdx.x; if(idx>=k*k) return;
  int u = idx/k, v = idx - u*k;
  int d = perm[u], pv = perm[v];
  float acc = 0.0f;
  int p0 = offD[d], p1 = offD[d+1];
  for(int p=p0;p<p1;p++) acc = fmaf(scE[eidD[p]], R[(size_t)rowD[p]*n + pv], acc);
  A[idx] = (u==v) ? 0.0f : acc;
}

__global__ void k_head2(const float* __restrict__ xs,const float* __restrict__ W1,
                        const float* __restrict__ b1,const float* __restrict__ W2,
                        const float* __restrict__ b2,float* out){
  __shared__ float h2[64];
  __shared__ float lg[10];
  int t = threadIdx.x;
  float s = b1[t];
  for(int q=0;q<640;q++) s = fmaf(xs[q], W1[q*64+t], s);
  h2[t] = fmaxf(s, 0.0f);
  __syncthreads();
  if(t < 10){
    float s2 = b2[t];
    for(int k=0;k<64;k++) s2 = fmaf(h2[k], W2[k*10+t], s2);
    lg[t] = s2;
  }
  __syncthreads();
  if(t == 0){
    float mx = lg[0];
    for(int i=1;i<10;i++) mx = fmaxf(mx, lg[i]);
    float se = 0.0f;
    for(int i=0;i<10;i++) se += expf(lg[i]-mx);
    float lse = mx + logf(se);
    for(int i=0;i<10;i++) out[i] = lg[i]-lse;
  }
}

// ---------------- host orchestration ----------------
extern "C" void kernel_launch(void* const* d_in, const int* in_sizes, int n_in,
                              void* d_out, int out_size, void* d_ws, size_t ws_size,
                              hipStream_t stream) {
  const int N0 = 1500, E = 24000, Z = 16, L = E + N0;
  const float* x0   = (const float*)d_in[0];
  const int* esrc   = (const int*)d_in[1];
  const int* edst   = (const int*)d_in[2];
  const float* W1   = (const float*)d_in[3];  const float* b1   = (const float*)d_in[4];
  const float* W2   = (const float*)d_in[5];  const float* b2   = (const float*)d_in[6];
  const float* W3   = (const float*)d_in[7];  const float* b3   = (const float*)d_in[8];
  const float* Wrel = (const float*)d_in[9];  const float* brel = (const float*)d_in[10];
  const float* Wroot= (const float*)d_in[11];
  const float* pW   = (const float*)d_in[12]; const float* pb   = (const float*)d_in[13];
  const float* leW1 = (const float*)d_in[14]; const float* leb1 = (const float*)d_in[15];
  const float* leW2 = (const float*)d_in[16]; const float* leW3 = (const float*)d_in[17];
  const float* leb3 = (const float*)d_in[18];
  const float* linW1= (const float*)d_in[19]; const float* linb1= (const float*)d_in[20];
  const float* linW2= (const float*)d_in[21]; const float* linb2= (const float*)d_in[22];
  float* out = (float*)d_out;

  float* ws = (float*)d_ws;
  size_t cur = 0;
  auto allocF = [&](size_t nf)->float*{ float* p = ws + cur; cur += (nf + 15) & ~(size_t)15; return p; };
  // contiguous zero block: xs | indeg | outdeg
  float* xs   = allocF(640);
  int* indeg  = (int*)allocF(1504);
  int* outdeg = (int*)allocF(1504);
  float* Xa  = allocF(96000); float* Xb  = allocF(96000); float* Y   = allocF(96000);
  float* XQ2 = allocF(96000); float* XC  = allocF(96000);
  float* mcol = allocF(1504); float* invd = allocF(1504);
  float* aN = allocF(1504); float* bN = allocF(1504); float* cN = allocF(1504);
  float* fit = allocF(1504); float* cntP = allocF(1504);
  int* pcnt = (int*)allocF(16);
  int* perm = (int*)allocF(1504);
  int* offD = (int*)allocF(1504); int* offS = (int*)allocF(1504);
  int* curD = (int*)allocF(1504); int* curS = (int*)allocF(1504);
  int* colS = (int*)allocF(25504); int* eidS = (int*)allocF(25504);
  int* rowD = (int*)allocF(25504); int* eidD = (int*)allocF(25504);
  float* sE = allocF(25504); float* scE = allocF(25504);
  int* cntp8 = (int*)allocF((size_t)Z*1504);
  float* aggp = allocF(16*1504);
  float* SEGP = allocF((size_t)Z*1504*64);
  float* Rbig = allocF((size_t)1500*1500);   // pool0 R; aliased as SCb afterwards
  float* SCb  = Rbig;
  float* A0  = allocF((size_t)1350*1350);
  float* A1s = allocF((size_t)1350*1350);
  const size_t BFSZ = (size_t)1350*4224/2 + 32;
  ushort* Abf = (ushort*)allocF(BFSZ);
  ushort* Bbf = (ushort*)allocF(BFSZ);
  ushort* Cbf = (ushort*)allocF(BFSZ);
  ushort* Dbf = (ushort*)allocF(BFSZ);

  dim3 B256(256);
  auto G1 = [&](size_t n){ return dim3((unsigned)((n + 255) / 256)); };
  auto ZF = [&](void* p, size_t nfloats){ k_zero<<<G1(nfloats),B256,0,stream>>>((float*)p, nfloats); };
  auto kcz = [&](int K){ return (int)(((K + Z*16 - 1) / (Z*16)) * 16); };

  // ---- prologue: zero (xs+indeg+outdeg contiguous), degrees, CSR ----
  ZF(xs, 640 + 1504 + 1504);
  k_deg<<<G1(E),B256,0,stream>>>(esrc, edst, indeg, outdeg, E);
  k_prefix2<<<dim3((N0+256)/256,2),B256,0,stream>>>(indeg, outdeg, offD, curD, offS, curS, N0);
  k_csr_fill2<<<G1(L),B256,0,stream>>>(esrc, edst, curS, colS, eidS, curD, rowD, eidD, E, N0);

  // ---- FEAST x3 (2 nodes each) ----
  auto feast = [&](const float* xin,int cin,const float* W,const float* bb,int hh,float* xout,float* macc){
    k_mm_small<<<G1((size_t)N0*hh),B256,0,stream>>>(xin, W, nullptr, Y, N0, cin, hh, 0);
    k_feast_gf<<<G1((size_t)N0*hh),B256,0,stream>>>(Y, offD, rowD, bb, xout, N0, hh, macc, 1.0f/N0);
  };
  feast(x0, 16, W1, b1, 32, Xa, nullptr);
  feast(Xa, 32, W2, b2, 64, Xb, nullptr);
  feast(Xb, 64, W3, b3, 64, Xa, xs + 0);
  float* X = Xa; float* XN = Xb;

  // ---- i=0 gconv_sparse (1 node) ----
  k_gconv_sparse_f<<<dim3((N0+3)/4),B256,0,stream>>>(X, offD, rowD, eidD, E, Wrel, brel, Wroot,
                                                     XN, N0, xs + 64, 1.0f/N0);
  { float* t = X; X = XN; XN = t; }

  // ---- pool 0 (sparse ASAP), n=1500 -> k=1350 ----
  {
    const int n = 1500, kk = 1350;
    k_xqmaxq<<<dim3((n+3)/4),B256,0,stream>>>(X, offD, rowD, pW, pb, XQ2, n);
    k_edge_score<<<G1(L),B256,0,stream>>>(esrc, edst, XQ2, X, sE, E, n);
    k_dstsoft<<<G1(n),B256,0,stream>>>(offD, eidD, sE, scE, n);
    k_xcabc0<<<dim3((n+3)/4),B256,0,stream>>>(offD, rowD, eidD, scE, X, XC,
                                              leW1, leb1, leW2, leW3, leb3, aN, bN, cN, pcnt, n);
    k_aggfit0<<<G1(n),B256,0,stream>>>(offD, rowD, aN, bN, cN, fit, n);
    k_rank_fused<0><<<G1(n),B256,0,stream>>>(fit, nullptr, nullptr, nullptr, nullptr, nullptr,
                                             XC, XN, n, kk, pcnt, perm);
    ZF(Rbig, (size_t)n*n);
    k_stage1n<<<G1(L),B256,0,stream>>>(esrc, edst, offS, colS, eidS, scE, Rbig, E, n);
    k_stage2p<<<G1((size_t)kk*kk),B256,0,stream>>>(perm, offD, rowD, eidD, scE, Rbig, A0, kk, n);
    { float* t = X; X = XN; XN = t; }
  }

  float* Acur = A0; float* Aoth = A1s;
  int nn = 1350;

  // ---- dense gconv (2 nodes) ----
  auto gconv_dense = [&](int layer){
    dim3 g(1, (nn+63)/64, Z);
    k_skinny<false,true,false,false><<<g,B256,0,stream>>>(Acur, nn, X, nullptr, SEGP, cntp8, nn, nn, kcz(nn));
    k_gconv_fuse<<<dim3((nn+3)/4),B256,0,stream>>>(SEGP, cntp8, Z,
        Wrel + (size_t)layer*4096, brel + layer*64, X, Wroot + (size_t)layer*4096,
        XN, nn, xs + (size_t)(layer+1)*64, 1.0f/nn);
    { float* t = X; X = XN; XN = t; }
  };

  // ---- dense ASAP pool ----
  auto asap_dense = [&](int kk, int p){
    {
      dim3 g(1, (nn+63)/64, Z);
      k_skinny<true,true,false,true><<<g,B256,0,stream>>>(Acur, nn, X, nullptr, SEGP, cntp8, nn, nn, kcz(nn));
    }
    k_poolq<<<dim3((nn+3)/4),B256,0,stream>>>(SEGP, cntp8, Z, pW + (size_t)p*4096, pb + p*64,
                                              X, Abf, Bbf, cntP, nn);
    {
      dim3 g((nn+63)/64, (nn+63)/64);
      k_gemm_mfma<1><<<g,B256,0,stream>>>(Abf, Bbf, SCb, nn, nn, nn, 192, Acur, nn);
    }
    k_smax_fused<<<dim3((nn+15)/16),B256,0,stream>>>(SCb, nn, mcol, invd);
    {
      dim3 g(1, (nn+63)/64, Z);
      k_skinny<false,false,true,false><<<g,B256,0,stream>>>(SCb, nn, X, mcol, SEGP, nullptr, nn, nn, kcz(nn));
    }
    k_xcabc_dense<<<dim3((nn+3)/4),B256,0,stream>>>(SEGP, Z, invd, XC,
        leW1 + p*64, leb1 + p, leW2 + p*64, leW3 + p*64, leb3 + p, aN, bN, cN, pcnt, nn);
    k_aggcol<<<G1((size_t)nn*16),B256,0,stream>>>(Acur, aN, aggp, nn);
    k_rank_fused<1><<<G1(nn),B256,0,stream>>>(nullptr, aggp, cntP, aN, bN, cN,
                                              XC, XN, nn, kk, pcnt, perm);
    const int Kp = (nn + 63) & ~63;
    const int K3 = 3*Kp;
    k_split3<<<G1((size_t)nn*Kp),B256,0,stream>>>(Acur, nn, nn, nn, Abf, Kp, 0);
    { dim3 gt((kk+31)/32, Kp/32);
      k_split3_Tdual<<<gt,B256,0,stream>>>(SCb, nn, kk, nn, perm, invd, mcol, Dbf, Bbf, Cbf, Kp); }
    { dim3 g((kk+63)/64, (nn+63)/64);
      k_gemm_mfma_tb<<<g,B256,0,stream>>>(Abf, Bbf, Cbf, Kp, nn, kk, K3); }
    { dim3 g((kk+63)/64, (kk+63)/64);
      k_gemm_mfma<2><<<g,B256,0,stream>>>(Dbf, Cbf, Aoth, kk, kk, kk, K3, nullptr, 0); }
    { float* t = X; X = XN; XN = t; }
    { float* t = Acur; Acur = Aoth; Aoth = t; }
    nn = kk;
  };

  gconv_dense(1);
  gconv_dense(2);
  asap_dense(1215, 1);
  gconv_dense(3);
  gconv_dense(4);
  asap_dense(1094, 2);
  gconv_dense(5);
  gconv_dense(6);
  asap_dense(985, 3);
  gconv_dense(7);
  gconv_dense(8);

  // ---- head (1 node) ----
  k_head2<<<1,64,0,stream>>>(xs, linW1, linb1, linW2, linb2, out);
}